// Round 1
// baseline (1518.174 us; speedup 1.0000x reference)
//
#include <hip/hip_runtime.h>
#include <hip/hip_bf16.h>

#define B_ 64
#define N_ 4096
#define C_ 256
#define K_ 8
#define NOUT 512
#define M_ (B_*N_)
#define ITERS_ 3
#define SCALE_ 0.0625f
#define EPS_ 1e-8f

typedef __attribute__((ext_vector_type(4))) float f32x4;
typedef __attribute__((ext_vector_type(8))) __bf16 bf16x8;
typedef __attribute__((ext_vector_type(8))) unsigned short ushort8;

__device__ __forceinline__ unsigned short f2bf(float f){
    union { float f; unsigned u; } v; v.f = f;
    unsigned r = v.u + 0x7fffu + ((v.u >> 16) & 1u);
    return (unsigned short)(r >> 16);
}
__device__ __forceinline__ float bf2f(unsigned short h){
    union { unsigned u; float f; } v; v.u = ((unsigned)h) << 16;
    return v.f;
}

// ---------------- prep: WT = [Wk|Wv]^T bf16, biasKV, slots init ----------------
__global__ void prep_kernel(const float* __restrict__ Wk, const float* __restrict__ bk,
                            const float* __restrict__ Wv, const float* __restrict__ bv,
                            const float* __restrict__ mu, const float* __restrict__ lsig,
                            const float* __restrict__ noise,
                            unsigned short* __restrict__ WT, float* __restrict__ biasKV,
                            float* __restrict__ slots){
    int idx = blockIdx.x * 256 + threadIdx.x;      // 0..131071
    int n = idx >> 8, c = idx & 255;
    float w = (n < 256) ? Wk[c*256 + n] : Wv[c*256 + (n - 256)];
    WT[n*256 + c] = f2bf(w);
    if (idx < NOUT) biasKV[idx] = (idx < 256) ? bk[idx] : bv[idx - 256];
    // slots init (same index space: B*K*C = 131072)
    int i = (idx >> 8) & 7;
    slots[idx] = mu[c] + expf(lsig[c]) * noise[i*256 + c];
}

// ---------------- fused LN(x) @ [Wk|Wv] + bias -> kv bf16 ----------------
// BM=64 rows, BN=512 (full), BK=64. 512 threads = 8 waves, wave w owns cols 64w..64w+63.
__global__ __launch_bounds__(512)
void lnkv_kernel(const float* __restrict__ x, const float* __restrict__ g, const float* __restrict__ bta,
                 const unsigned short* __restrict__ WT, const float* __restrict__ biasKV,
                 unsigned short* __restrict__ kv){
    __shared__ __align__(16) char AT[64*128];   // bf16 [64 rows][64 k], XOR-swizzled
    __shared__ float s_mean[64], s_rstd[64];
    __shared__ float s_g[256], s_b[256];
    const int t = threadIdx.x;
    const int r0 = blockIdx.x * 64;
    const int row = t >> 3, sl = t & 7;

    if (t < 256){ s_g[t] = g[t]; s_b[t] = bta[t]; }

    // per-row stats (biased var, eps 1e-5)
    {
        const float* xr = x + (size_t)(r0 + row) * C_;
        float sum = 0.f, sq = 0.f;
        #pragma unroll
        for (int u = 0; u < 8; ++u){
            const float4 v = *(const float4*)(xr + sl*4 + u*32);
            sum += v.x + v.y + v.z + v.w;
            sq  += v.x*v.x + v.y*v.y + v.z*v.z + v.w*v.w;
        }
        #pragma unroll
        for (int m = 1; m < 8; m <<= 1){ sum += __shfl_xor(sum, m); sq += __shfl_xor(sq, m); }
        if (sl == 0){
            float mean = sum * (1.f/256.f);
            float var  = sq  * (1.f/256.f) - mean*mean;
            s_mean[row] = mean; s_rstd[row] = rsqrtf(var + 1e-5f);
        }
    }
    __syncthreads();

    const int w = t >> 6, l = t & 63;
    const int lr = l & 15, lg = l >> 4;
    f32x4 acc[4][4];
    #pragma unroll
    for (int m = 0; m < 4; ++m)
        #pragma unroll
        for (int n = 0; n < 4; ++n) acc[m][n] = (f32x4){0.f,0.f,0.f,0.f};

    for (int kc = 0; kc < 256; kc += 64){
        // stage A: re-read x chunk (L1/L2 hot), normalize, bf16, swizzled LDS write
        {
            const float* xp = x + (size_t)(r0 + row) * C_ + kc + sl*8;
            float4 a0 = *(const float4*)xp;
            float4 a1 = *(const float4*)(xp + 4);
            float mean = s_mean[row], rs = s_rstd[row];
            ushort8 pk;
            const float* a0p = (const float*)&a0;
            const float* a1p = (const float*)&a1;
            #pragma unroll
            for (int e = 0; e < 4; ++e){
                int c0 = kc + sl*8 + e;
                pk[e]   = f2bf((a0p[e] - mean) * rs * s_g[c0]     + s_b[c0]);
                pk[4+e] = f2bf((a1p[e] - mean) * rs * s_g[c0 + 4] + s_b[c0 + 4]);
            }
            int byte = row*128 + sl*16; byte ^= (row & 7) << 4;
            *(ushort8*)(AT + byte) = pk;
        }
        __syncthreads();
        #pragma unroll
        for (int kk = 0; kk < 64; kk += 32){
            bf16x8 af[4], bfr[4];
            #pragma unroll
            for (int m = 0; m < 4; ++m){
                int rr = 16*m + lr;
                int byte = rr*128 + (kk + 8*lg)*2; byte ^= (rr & 7) << 4;
                af[m] = __builtin_bit_cast(bf16x8, *(const ushort8*)(AT + byte));
            }
            #pragma unroll
            for (int n = 0; n < 4; ++n){
                int nrow = w*64 + 16*n + lr;
                bfr[n] = __builtin_bit_cast(bf16x8, *(const ushort8*)(WT + nrow*256 + kc + kk + 8*lg));
            }
            #pragma unroll
            for (int m = 0; m < 4; ++m)
                #pragma unroll
                for (int n = 0; n < 4; ++n)
                    acc[m][n] = __builtin_amdgcn_mfma_f32_16x16x32_bf16(af[m], bfr[n], acc[m][n], 0, 0, 0);
        }
        __syncthreads();
    }
    // epilogue: D[row,col]: col = 16n+(l&15), row = 16m+4*(l>>4)+r
    #pragma unroll
    for (int n = 0; n < 4; ++n){
        int col = w*64 + 16*n + lr;
        float bias = biasKV[col];
        #pragma unroll
        for (int m = 0; m < 4; ++m){
            #pragma unroll
            for (int r = 0; r < 4; ++r){
                int rowg = r0 + 16*m + 4*lg + r;
                kv[(size_t)rowg * NOUT + col] = f2bf(acc[m][n][r] + bias);
            }
        }
    }
}

// ---------------- per-iter: q = LN_s(slots) @ Wq + bq ----------------
__global__ void q_kernel(const float* __restrict__ slots, const float* __restrict__ Wq,
                         const float* __restrict__ bq, const float* __restrict__ gs,
                         const float* __restrict__ bs, float* __restrict__ qout){
    __shared__ float sn[8][264];
    const int t = threadIdx.x, b = blockIdx.x;
    const int i = t >> 5, c0 = (t & 31) * 8;
    {
        const float* sp = slots + ((size_t)b*K_ + i) * C_ + c0;
        float v[8] __attribute__((aligned(16)));
        *(float4*)v       = *(const float4*)sp;
        *(float4*)(v + 4) = *(const float4*)(sp + 4);
        float sum = 0.f, sq = 0.f;
        #pragma unroll
        for (int e = 0; e < 8; ++e){ sum += v[e]; sq += v[e]*v[e]; }
        #pragma unroll
        for (int m = 1; m < 32; m <<= 1){ sum += __shfl_xor(sum, m); sq += __shfl_xor(sq, m); }
        float mean = sum * (1.f/256.f);
        float rstd = rsqrtf(sq * (1.f/256.f) - mean*mean + 1e-5f);
        #pragma unroll
        for (int e = 0; e < 8; ++e){
            int c = c0 + e;
            sn[i][c] = (v[e] - mean) * rstd * gs[c] + bs[c];
        }
    }
    __syncthreads();
    const int n = t;
    float acc[8];
    float bias = bq[n];
    #pragma unroll
    for (int ii = 0; ii < 8; ++ii) acc[ii] = bias;
    for (int c = 0; c < 256; c += 4){
        float w0 = Wq[(size_t)(c+0)*256 + n];
        float w1 = Wq[(size_t)(c+1)*256 + n];
        float w2 = Wq[(size_t)(c+2)*256 + n];
        float w3 = Wq[(size_t)(c+3)*256 + n];
        #pragma unroll
        for (int ii = 0; ii < 8; ++ii){
            const float4 s4 = *(const float4*)&sn[ii][c];
            acc[ii] += s4.x*w0 + s4.y*w1 + s4.z*w2 + s4.w*w3;
        }
    }
    #pragma unroll
    for (int ii = 0; ii < 8; ++ii)
        qout[((size_t)b*K_ + ii)*C_ + n] = acc[ii];
}

// ---------------- per-iter: dots -> slot-softmax -> partial U',S ----------------
// grid (B, 8): 512 j per block. Thread t owns j=t and j=t+256 (all 8 slots -> local softmax).
__global__ void attn_kernel(const float* __restrict__ q, const unsigned short* __restrict__ kv,
                            float* __restrict__ Spart, float* __restrict__ Upart){
    __shared__ __align__(16) char kt[512*64];   // bf16 [512 j][32 c], slot-XOR swizzled; reused as reduce scratch
    __shared__ float qs[8][264];
    __shared__ float ps[512][8];
    const int t = threadIdx.x, b = blockIdx.x, jb = blockIdx.y;
    const size_t row0 = (size_t)b * N_ + (size_t)jb * 512;
    {
        int i = t >> 5, c0 = (t & 31) * 8;
        const float* qp = q + ((size_t)b*K_ + i)*C_ + c0;
        *(float4*)&qs[i][c0]     = *(const float4*)qp;
        *(float4*)&qs[i][c0 + 4] = *(const float4*)(qp + 4);
    }
    float d[2][8];
    #pragma unroll
    for (int jj = 0; jj < 2; ++jj)
        #pragma unroll
        for (int i = 0; i < 8; ++i) d[jj][i] = 0.f;

    for (int cc = 0; cc < 256; cc += 32){
        __syncthreads();
        #pragma unroll
        for (int s = 0; s < 8; ++s){
            int r = s*64 + (t >> 2);
            int slot = (t & 3) ^ (r & 3);
            ushort8 kvv = *(const ushort8*)(kv + (row0 + r)*NOUT + cc + (t & 3)*8);
            *(ushort8*)(kt + r*64 + slot*16) = kvv;
        }
        __syncthreads();
        #pragma unroll
        for (int sub = 0; sub < 4; ++sub){
            const int cgl = cc + sub*8;
            ushort8 k0 = *(const ushort8*)(kt + t*64       + ((sub ^ (t & 3)) * 16));
            ushort8 k1 = *(const ushort8*)(kt + (t+256)*64 + ((sub ^ (t & 3)) * 16));
            float kf0[8], kf1[8];
            #pragma unroll
            for (int e = 0; e < 8; ++e){ kf0[e] = bf2f(k0[e]); kf1[e] = bf2f(k1[e]); }
            #pragma unroll
            for (int i = 0; i < 8; ++i){
                const float4 qa = *(const float4*)&qs[i][cgl];
                const float4 qb = *(const float4*)&qs[i][cgl + 4];
                d[0][i] += qa.x*kf0[0] + qa.y*kf0[1] + qa.z*kf0[2] + qa.w*kf0[3]
                         + qb.x*kf0[4] + qb.y*kf0[5] + qb.z*kf0[6] + qb.w*kf0[7];
                d[1][i] += qa.x*kf1[0] + qa.y*kf1[1] + qa.z*kf1[2] + qa.w*kf1[3]
                         + qb.x*kf1[4] + qb.y*kf1[5] + qb.z*kf1[6] + qb.w*kf1[7];
            }
        }
    }
    // slot-axis softmax (thread-local), + EPS; partial key-sums
    float s8[8] __attribute__((aligned(16)));
    #pragma unroll
    for (int i = 0; i < 8; ++i) s8[i] = 0.f;
    #pragma unroll
    for (int jj = 0; jj < 2; ++jj){
        float mx = d[jj][0];
        #pragma unroll
        for (int i = 1; i < 8; ++i) mx = fmaxf(mx, d[jj][i]);
        float e[8], ssum = 0.f;
        #pragma unroll
        for (int i = 0; i < 8; ++i){ e[i] = __expf((d[jj][i] - mx) * SCALE_); ssum += e[i]; }
        float inv = 1.f / ssum;
        #pragma unroll
        for (int i = 0; i < 8; ++i){
            float p = e[i]*inv + EPS_;
            ps[t + jj*256][i] = p;
            s8[i] += p;
        }
    }
    __syncthreads();                       // kt reads done; ps complete
    float* scr = (float*)kt;
    *(float4*)&scr[t*8]     = *(float4*)&s8[0];
    *(float4*)&scr[t*8 + 4] = *(float4*)&s8[4];
    __syncthreads();
    if (t < 64){
        int i = t >> 3, part = t & 7;
        float s = 0.f;
        for (int u = 0; u < 32; ++u) s += scr[(part*32 + u)*8 + i];
        #pragma unroll
        for (int m = 1; m < 8; m <<= 1) s += __shfl_xor(s, m);
        if (part == 0) Spart[((size_t)b*8 + jb)*8 + i] = s;
    }
    __syncthreads();
    // PV: thread (jseg=t>>5, cg=t&31) accumulates U'[i][cg*8..+8) over its 64 j (v read from global, coalesced)
    const int jseg = t >> 5, cg = t & 31;
    float ua[64] __attribute__((aligned(16)));
    #pragma unroll
    for (int e = 0; e < 64; ++e) ua[e] = 0.f;
    const unsigned short* vb = kv + row0*NOUT + 256 + cg*8;
    for (int jj = 0; jj < 64; ++jj){
        int j = jseg*64 + jj;
        ushort8 vv = *(const ushort8*)(vb + (size_t)j*NOUT);
        float vf[8];
        #pragma unroll
        for (int e = 0; e < 8; ++e) vf[e] = bf2f(vv[e]);
        const float4 p0 = *(const float4*)&ps[j][0];
        const float4 p1 = *(const float4*)&ps[j][4];
        const float pr[8] = {p0.x, p0.y, p0.z, p0.w, p1.x, p1.y, p1.z, p1.w};
        #pragma unroll
        for (int i = 0; i < 8; ++i)
            #pragma unroll
            for (int e = 0; e < 8; ++e)
                ua[i*8 + e] += pr[i] * vf[e];
    }
    // tree-reduce the 8 jsegs via scr (32 KB)
    for (int bound = 4; bound >= 1; bound >>= 1){
        __syncthreads();
        if (jseg >= bound && jseg < 2*bound){
            float* dst = &scr[((jseg - bound)*32 + cg) * 64];
            #pragma unroll
            for (int e4 = 0; e4 < 64; e4 += 4) *(float4*)&dst[e4] = *(float4*)&ua[e4];
        }
        __syncthreads();
        if (jseg < bound){
            const float* src = &scr[(jseg*32 + cg) * 64];
            #pragma unroll
            for (int e = 0; e < 64; ++e) ua[e] += src[e];
        }
    }
    if (jseg == 0){
        float* up = Upart + (((size_t)b*8 + jb)*8) * C_ + cg*8;
        #pragma unroll
        for (int i = 0; i < 8; ++i){
            *(float4*)&up[(size_t)i*C_]     = *(float4*)&ua[i*8];
            *(float4*)&up[(size_t)i*C_ + 4] = *(float4*)&ua[i*8 + 4];
        }
    }
}

// ---------------- per-iter: finalize updates + GRUCell -> slots2 ----------------
// grid (B, 4): block owns 64 output cols.
__global__ void gru_kernel(const float* __restrict__ slots, const float* __restrict__ Spart,
                           const float* __restrict__ Upart, const float* __restrict__ W_ih,
                           const float* __restrict__ b_ih, const float* __restrict__ W_hh,
                           const float* __restrict__ b_hh, float* __restrict__ slots2){
    __shared__ float upd[8][260], sp[8][260];
    const int t = threadIdx.x, b = blockIdx.x, cg = blockIdx.y;
    const int i = t >> 5, c0 = (t & 31) * 8;
    {
        float us[8];
        #pragma unroll
        for (int e = 0; e < 8; ++e) us[e] = 0.f;
        for (int jb = 0; jb < 8; ++jb){
            const float* up = Upart + (((size_t)b*8 + jb)*8 + i)*C_ + c0;
            float4 u0 = *(const float4*)up;
            float4 u1 = *(const float4*)(up + 4);
            us[0]+=u0.x; us[1]+=u0.y; us[2]+=u0.z; us[3]+=u0.w;
            us[4]+=u1.x; us[5]+=u1.y; us[6]+=u1.z; us[7]+=u1.w;
        }
        float S = 0.f;
        for (int jb = 0; jb < 8; ++jb) S += Spart[((size_t)b*8 + jb)*8 + i];
        float invS = 1.f / S;
        const float* slp = slots + ((size_t)b*8 + i)*C_ + c0;
        float4 s0v = *(const float4*)slp;
        float4 s1v = *(const float4*)(slp + 4);
        #pragma unroll
        for (int e = 0; e < 8; ++e) upd[i][c0 + e] = us[e] * invS;
        sp[i][c0+0]=s0v.x; sp[i][c0+1]=s0v.y; sp[i][c0+2]=s0v.z; sp[i][c0+3]=s0v.w;
        sp[i][c0+4]=s1v.x; sp[i][c0+5]=s1v.y; sp[i][c0+6]=s1v.z; sp[i][c0+7]=s1v.w;
    }
    __syncthreads();
    const int n = cg*64 + (t & 31);
    const int n2 = n + 32;
    float xr0 = b_ih[n],     xr1 = b_ih[n2];
    float xz0 = b_ih[256+n], xz1 = b_ih[256+n2];
    float xn0 = b_ih[512+n], xn1 = b_ih[512+n2];
    float hr0 = b_hh[n],     hr1 = b_hh[n2];
    float hz0 = b_hh[256+n], hz1 = b_hh[256+n2];
    float hn0 = b_hh[512+n], hn1 = b_hh[512+n2];
    #pragma unroll 2
    for (int c = 0; c < 256; ++c){
        float uv = upd[i][c], sv = sp[i][c];
        const float* wi = W_ih + (size_t)c * 768;
        const float* wh = W_hh + (size_t)c * 768;
        xr0 += uv*wi[n];      xr1 += uv*wi[n2];
        xz0 += uv*wi[256+n];  xz1 += uv*wi[256+n2];
        xn0 += uv*wi[512+n];  xn1 += uv*wi[512+n2];
        hr0 += sv*wh[n];      hr1 += sv*wh[n2];
        hz0 += sv*wh[256+n];  hz1 += sv*wh[256+n2];
        hn0 += sv*wh[512+n];  hn1 += sv*wh[512+n2];
    }
    float r0v = 1.f/(1.f + __expf(-(xr0 + hr0)));
    float z0v = 1.f/(1.f + __expf(-(xz0 + hz0)));
    float nn0 = tanhf(xn0 + r0v*hn0);
    float o0  = (1.f - z0v)*nn0 + z0v*sp[i][n];
    float r1v = 1.f/(1.f + __expf(-(xr1 + hr1)));
    float z1v = 1.f/(1.f + __expf(-(xz1 + hz1)));
    float nn1 = tanhf(xn1 + r1v*hn1);
    float o1  = (1.f - z1v)*nn1 + z1v*sp[i][n2];
    slots2[((size_t)b*8 + i)*C_ + n]  = o0;
    slots2[((size_t)b*8 + i)*C_ + n2] = o1;
}

// ---------------- per-iter: FFN with residual -> slots (and d_out) ----------------
__global__ void ffn_kernel(const float* __restrict__ slots2, const float* __restrict__ gf,
                           const float* __restrict__ bf, const float* __restrict__ W1,
                           const float* __restrict__ b1, const float* __restrict__ W2,
                           const float* __restrict__ b2, float* __restrict__ slots,
                           float* __restrict__ dout){
    __shared__ float s0[8][260], pre[8][260], hb[8][260];
    const int t = threadIdx.x, b = blockIdx.x;
    const int i = t >> 5, c0 = (t & 31) * 8;
    {
        const float* spt = slots2 + ((size_t)b*8 + i)*C_ + c0;
        float v[8] __attribute__((aligned(16)));
        *(float4*)v       = *(const float4*)spt;
        *(float4*)(v + 4) = *(const float4*)(spt + 4);
        float sum = 0.f, sq = 0.f;
        #pragma unroll
        for (int e = 0; e < 8; ++e){ sum += v[e]; sq += v[e]*v[e]; }
        #pragma unroll
        for (int m = 1; m < 32; m <<= 1){ sum += __shfl_xor(sum, m); sq += __shfl_xor(sq, m); }
        float mean = sum * (1.f/256.f);
        float rstd = rsqrtf(sq * (1.f/256.f) - mean*mean + 1e-5f);
        #pragma unroll
        for (int e = 0; e < 8; ++e){
            int c = c0 + e;
            s0[i][c]  = v[e];
            pre[i][c] = (v[e] - mean) * rstd * gf[c] + bf[c];
        }
    }
    __syncthreads();
    const int m0 = t & 31;
    float hacc[8];
    #pragma unroll
    for (int u = 0; u < 8; ++u) hacc[u] = b1[m0 + 32*u];
    for (int c = 0; c < 256; ++c){
        float pv = pre[i][c];
        const float* w1r = W1 + (size_t)c * 256;
        #pragma unroll
        for (int u = 0; u < 8; ++u) hacc[u] += pv * w1r[m0 + 32*u];
    }
    #pragma unroll
    for (int u = 0; u < 8; ++u) hb[i][m0 + 32*u] = fmaxf(hacc[u], 0.f);
    __syncthreads();
    float oacc[8];
    #pragma unroll
    for (int u = 0; u < 8; ++u) oacc[u] = b2[m0 + 32*u];
    for (int mm = 0; mm < 256; ++mm){
        float hv = hb[i][mm];
        const float* w2r = W2 + (size_t)mm * 256;
        #pragma unroll
        for (int u = 0; u < 8; ++u) oacc[u] += hv * w2r[m0 + 32*u];
    }
    #pragma unroll
    for (int u = 0; u < 8; ++u){
        int n = m0 + 32*u;
        float val = s0[i][n] + oacc[u];
        size_t off = ((size_t)b*8 + i)*C_ + n;
        slots[off] = val;
        dout[off]  = val;
    }
}

extern "C" void kernel_launch(void* const* d_in, const int* in_sizes, int n_in,
                              void* d_out, int out_size, void* d_ws, size_t ws_size,
                              hipStream_t stream){
    const float* inputs = (const float*)d_in[0];
    const float* noise  = (const float*)d_in[1];
    const float* mu     = (const float*)d_in[2];
    const float* lsig   = (const float*)d_in[3];
    const float* g_in   = (const float*)d_in[4];
    const float* b_in   = (const float*)d_in[5];
    const float* g_s    = (const float*)d_in[6];
    const float* b_s    = (const float*)d_in[7];
    const float* g_ff   = (const float*)d_in[8];
    const float* b_ff   = (const float*)d_in[9];
    const float* Wq     = (const float*)d_in[10];
    const float* bq     = (const float*)d_in[11];
    const float* Wk     = (const float*)d_in[12];
    const float* bk     = (const float*)d_in[13];
    const float* Wv     = (const float*)d_in[14];
    const float* bv     = (const float*)d_in[15];
    const float* W_ih   = (const float*)d_in[16];
    const float* b_ih   = (const float*)d_in[17];
    const float* W_hh   = (const float*)d_in[18];
    const float* b_hh   = (const float*)d_in[19];
    const float* W1     = (const float*)d_in[20];
    const float* b1     = (const float*)d_in[21];
    const float* W2     = (const float*)d_in[22];
    const float* b2     = (const float*)d_in[23];

    char* ws = (char*)d_ws;
    unsigned short* WT  = (unsigned short*)(ws);              // 256 KB
    float* biasKV       = (float*)(ws + ((size_t)1  << 20));  // 2 KB
    float* qbuf         = (float*)(ws + ((size_t)2  << 20));  // 512 KB
    float* slots        = (float*)(ws + ((size_t)3  << 20));  // 512 KB
    float* Spart        = (float*)(ws + ((size_t)4  << 20));  // 16 KB
    float* Upart        = (float*)(ws + ((size_t)5  << 20));  // 4 MB
    float* slots2       = (float*)(ws + ((size_t)10 << 20));  // 512 KB
    unsigned short* kv  = (unsigned short*)(ws + ((size_t)16 << 20)); // 256 MB

    prep_kernel<<<512, 256, 0, stream>>>(Wk, bk, Wv, bv, mu, lsig, noise, WT, biasKV, slots);
    lnkv_kernel<<<M_/64, 512, 0, stream>>>(inputs, g_in, b_in, WT, biasKV, kv);
    for (int it = 0; it < ITERS_; ++it){
        q_kernel<<<B_, 256, 0, stream>>>(slots, Wq, bq, g_s, b_s, qbuf);
        attn_kernel<<<dim3(B_, 8), 256, 0, stream>>>(qbuf, kv, Spart, Upart);
        gru_kernel<<<dim3(B_, 4), 256, 0, stream>>>(slots, Spart, Upart, W_ih, b_ih, W_hh, b_hh, slots2);
        ffn_kernel<<<B_, 256, 0, stream>>>(slots2, g_ff, b_ff, W1, b1, W2, b2, slots, (float*)d_out);
    }
}

// Round 2
// 1336.198 us; speedup vs baseline: 1.1362x; 1.1362x over previous
//
#include <hip/hip_runtime.h>
#include <hip/hip_bf16.h>

#define B_ 64
#define N_ 4096
#define C_ 256
#define K_ 8
#define NOUT 512
#define M_ (B_*N_)
#define ITERS_ 3
#define SCALE_ 0.0625f
#define EPS_ 1e-8f

typedef __attribute__((ext_vector_type(4))) float f32x4;
typedef __attribute__((ext_vector_type(8))) __bf16 bf16x8;
typedef __attribute__((ext_vector_type(8))) unsigned short ushort8;
typedef __attribute__((ext_vector_type(4))) unsigned short ushort4v;

__device__ __forceinline__ unsigned short f2bf(float f){
    union { float f; unsigned u; } v; v.f = f;
    unsigned r = v.u + 0x7fffu + ((v.u >> 16) & 1u);
    return (unsigned short)(r >> 16);
}
__device__ __forceinline__ float bf2f(unsigned short h){
    union { unsigned u; float f; } v; v.u = ((unsigned)h) << 16;
    return v.f;
}

// ---------------- prep: WTf = [Wk|Wv]^T bf16 (MFMA-fragment-tiled), biasKV, slots init ----------------
// WTf layout: tile (ntile=n>>4, kchunk=c>>5) of 16n x 32c -> 512 elems; within tile,
// lane = (n&15) + 16*((c>>3)&3), elem = c&7  => A-frag read is lane-contiguous 1KB.
__global__ void prep_kernel(const float* __restrict__ Wk, const float* __restrict__ bk,
                            const float* __restrict__ Wv, const float* __restrict__ bv,
                            const float* __restrict__ mu, const float* __restrict__ lsig,
                            const float* __restrict__ noise,
                            unsigned short* __restrict__ WTf, float* __restrict__ biasKV,
                            float* __restrict__ slots){
    int idx = blockIdx.x * 256 + threadIdx.x;      // 0..131071
    int c = idx >> 9, n = idx & 511;               // coalesced over n for W reads
    float w = (n < 256) ? Wk[c*256 + n] : Wv[c*256 + (n - 256)];
    int tile = (n >> 4) * 8 + (c >> 5);
    int lane = (n & 15) + (((c >> 3) & 3) << 4);
    WTf[tile*512 + lane*8 + (c & 7)] = f2bf(w);
    if (idx < NOUT) biasKV[idx] = (idx < 256) ? bk[idx] : bv[idx - 256];
    // slots init (B*K*C = 131072)
    int sc = idx & 255;
    int si = (idx >> 8) & 7;
    slots[idx] = mu[sc] + expf(lsig[sc]) * noise[si*256 + sc];
}

// ---------------- fused LN(x) @ [Wk|Wv] + bias -> kv bf16 ----------------
// BM=64 rows, full N=512, full K=256. 512 threads = 8 waves; wave w owns cols [64w,64w+64).
// A=W (global, fragment-tiled), B=LN(x) (LDS, chunk-XOR swizzle). One barrier before MFMA.
// Output staged through LDS (reuse A-tile) in 2 rounds -> 64B/thread coalesced stores.
__global__ __launch_bounds__(512, 4)
void lnkv_kernel(const float* __restrict__ x, const float* __restrict__ g, const float* __restrict__ bta,
                 const unsigned short* __restrict__ WTf, const float* __restrict__ biasKV,
                 unsigned short* __restrict__ kv){
    __shared__ __align__(16) unsigned short A[64*256];   // 32 KB: bf16 A-tile, then out-staging
    const int t = threadIdx.x;
    const int r0 = blockIdx.x * 64;
    const int row = t >> 3, sl = t & 7;

    // single-pass load + stats (8 lanes per row)
    float v[32];
    {
        const float* xr = x + (size_t)(r0 + row) * C_;
        #pragma unroll
        for (int q = 0; q < 4; ++q){
            *(float4*)&v[q*8]     = *(const float4*)(xr + q*64 + sl*8);
            *(float4*)&v[q*8 + 4] = *(const float4*)(xr + q*64 + sl*8 + 4);
        }
        float sum = 0.f, sq = 0.f;
        #pragma unroll
        for (int e = 0; e < 32; ++e){ sum += v[e]; sq += v[e]*v[e]; }
        #pragma unroll
        for (int m = 1; m < 8; m <<= 1){ sum += __shfl_xor(sum, m); sq += __shfl_xor(sq, m); }
        float mean = sum * (1.f/256.f);
        float rstd = rsqrtf(sq * (1.f/256.f) - mean*mean + 1e-5f);
        #pragma unroll
        for (int q = 0; q < 4; ++q){
            float4 g0 = *(const float4*)(g + q*64 + sl*8);
            float4 g1 = *(const float4*)(g + q*64 + sl*8 + 4);
            float4 b0 = *(const float4*)(bta + q*64 + sl*8);
            float4 b1 = *(const float4*)(bta + q*64 + sl*8 + 4);
            const float* gp0 = (const float*)&g0; const float* gp1 = (const float*)&g1;
            const float* bp0 = (const float*)&b0; const float* bp1 = (const float*)&b1;
            ushort8 pk;
            #pragma unroll
            for (int e = 0; e < 4; ++e){
                pk[e]   = f2bf((v[q*8+e]   - mean) * rstd * gp0[e] + bp0[e]);
                pk[4+e] = f2bf((v[q*8+4+e] - mean) * rstd * gp1[e] + bp1[e]);
            }
            int ch = (q*8 + sl) ^ (row & 7);
            *(ushort8*)&A[row*256 + ch*8] = pk;
        }
    }
    __syncthreads();

    const int w = t >> 6, l = t & 63, lr = l & 15, lg = l >> 4;
    f32x4 acc[4][4];   // [nt][mt]
    #pragma unroll
    for (int nt = 0; nt < 4; ++nt)
        #pragma unroll
        for (int mt = 0; mt < 4; ++mt) acc[nt][mt] = (f32x4){0.f,0.f,0.f,0.f};

    #pragma unroll
    for (int k = 0; k < 8; ++k){
        bf16x8 wf[4], xf[4];
        #pragma unroll
        for (int nt = 0; nt < 4; ++nt)
            wf[nt] = __builtin_bit_cast(bf16x8,
                *(const ushort8*)(WTf + (((w*4 + nt)*8 + k) << 9) + l*8));
        #pragma unroll
        for (int mt = 0; mt < 4; ++mt){
            int m = mt*16 + lr;
            int ch = (k*4 + lg) ^ (m & 7);
            xf[mt] = __builtin_bit_cast(bf16x8, *(const ushort8*)&A[m*256 + ch*8]);
        }
        #pragma unroll
        for (int nt = 0; nt < 4; ++nt)
            #pragma unroll
            for (int mt = 0; mt < 4; ++mt)
                acc[nt][mt] = __builtin_amdgcn_mfma_f32_16x16x32_bf16(wf[nt], xf[mt], acc[nt][mt], 0, 0, 0);
    }
    __syncthreads();   // all A-tile reads complete; LDS now reusable

    // D-layout (swapped): lane holds cols m = 16mt+lr, rows n = 64w+16nt+4lg+r (4 consecutive n).
    char* S = (char*)A;
    const int rnd = w >> 2, sw = w & 3;
    #pragma unroll
    for (int r = 0; r < 2; ++r){
        if (rnd == r){
            #pragma unroll
            for (int nt = 0; nt < 4; ++nt){
                float4 b4 = *(const float4*)(biasKV + w*64 + nt*16 + lg*4);
                #pragma unroll
                for (int mt = 0; mt < 4; ++mt){
                    int m = mt*16 + lr;
                    ushort4v pk;
                    pk[0] = f2bf(acc[nt][mt][0] + b4.x);
                    pk[1] = f2bf(acc[nt][mt][1] + b4.y);
                    pk[2] = f2bf(acc[nt][mt][2] + b4.z);
                    pk[3] = f2bf(acc[nt][mt][3] + b4.w);
                    int byte = sw*8192 + m*128 + ((nt*32 + lg*8) ^ ((m & 15) << 3));
                    *(ushort4v*)(S + byte) = pk;
                }
            }
        }
        __syncthreads();
        {
            int swp = t >> 7, rem = t & 127, m = rem >> 1, half = rem & 1;
            unsigned short tmp[32];
            #pragma unroll
            for (int cck = 0; cck < 8; ++cck){
                int byte = swp*8192 + m*128 + ((half*64 + cck*8) ^ ((m & 15) << 3));
                *(ushort4v*)&tmp[cck*4] = *(const ushort4v*)(S + byte);
            }
            unsigned short* dst = kv + (size_t)(r0 + m)*NOUT + (r*4 + swp)*64 + half*32;
            *(ushort8*)(dst)      = *(ushort8*)&tmp[0];
            *(ushort8*)(dst + 8)  = *(ushort8*)&tmp[8];
            *(ushort8*)(dst + 16) = *(ushort8*)&tmp[16];
            *(ushort8*)(dst + 24) = *(ushort8*)&tmp[24];
        }
        __syncthreads();
    }
}

// ---------------- per-iter: q = LN_s(slots) @ Wq + bq  (grid (B,8): 32 cols/block) ----------------
__global__ void q_kernel(const float* __restrict__ slots, const float* __restrict__ Wq,
                         const float* __restrict__ bq, const float* __restrict__ gs,
                         const float* __restrict__ bs, float* __restrict__ qout){
    __shared__ float sn[8][264];
    const int t = threadIdx.x, b = blockIdx.x, qg = blockIdx.y;
    const int i = t >> 5, c0 = (t & 31) * 8;
    {
        const float* sp = slots + ((size_t)b*K_ + i) * C_ + c0;
        float v[8] __attribute__((aligned(16)));
        *(float4*)v       = *(const float4*)sp;
        *(float4*)(v + 4) = *(const float4*)(sp + 4);
        float sum = 0.f, sq = 0.f;
        #pragma unroll
        for (int e = 0; e < 8; ++e){ sum += v[e]; sq += v[e]*v[e]; }
        #pragma unroll
        for (int m = 1; m < 32; m <<= 1){ sum += __shfl_xor(sum, m); sq += __shfl_xor(sq, m); }
        float mean = sum * (1.f/256.f);
        float rstd = rsqrtf(sq * (1.f/256.f) - mean*mean + 1e-5f);
        #pragma unroll
        for (int e = 0; e < 8; ++e){
            int c = c0 + e;
            sn[i][c] = (v[e] - mean) * rstd * gs[c] + bs[c];
        }
    }
    __syncthreads();
    const int col = qg*32 + (t & 31);
    float acc = bq[col];
    #pragma unroll 4
    for (int c = 0; c < 256; ++c)
        acc += sn[i][c] * Wq[(size_t)c*256 + col];
    qout[((size_t)b*K_ + i)*C_ + col] = acc;
}

// ---------------- per-iter: dots -> slot-softmax -> partial U',S ----------------
__global__ void attn_kernel(const float* __restrict__ q, const unsigned short* __restrict__ kv,
                            float* __restrict__ Spart, float* __restrict__ Upart){
    __shared__ __align__(16) char kt[512*64];
    __shared__ float qs[8][264];
    __shared__ float ps[512][8];
    const int t = threadIdx.x, b = blockIdx.x, jb = blockIdx.y;
    const size_t row0 = (size_t)b * N_ + (size_t)jb * 512;
    {
        int i = t >> 5, c0 = (t & 31) * 8;
        const float* qp = q + ((size_t)b*K_ + i)*C_ + c0;
        *(float4*)&qs[i][c0]     = *(const float4*)qp;
        *(float4*)&qs[i][c0 + 4] = *(const float4*)(qp + 4);
    }
    float d[2][8];
    #pragma unroll
    for (int jj = 0; jj < 2; ++jj)
        #pragma unroll
        for (int i = 0; i < 8; ++i) d[jj][i] = 0.f;

    for (int cc = 0; cc < 256; cc += 32){
        __syncthreads();
        #pragma unroll
        for (int s = 0; s < 8; ++s){
            int r = s*64 + (t >> 2);
            int slot = (t & 3) ^ (r & 3);
            ushort8 kvv = *(const ushort8*)(kv + (row0 + r)*NOUT + cc + (t & 3)*8);
            *(ushort8*)(kt + r*64 + slot*16) = kvv;
        }
        __syncthreads();
        #pragma unroll
        for (int sub = 0; sub < 4; ++sub){
            const int cgl = cc + sub*8;
            ushort8 k0 = *(const ushort8*)(kt + t*64       + ((sub ^ (t & 3)) * 16));
            ushort8 k1 = *(const ushort8*)(kt + (t+256)*64 + ((sub ^ (t & 3)) * 16));
            float kf0[8], kf1[8];
            #pragma unroll
            for (int e = 0; e < 8; ++e){ kf0[e] = bf2f(k0[e]); kf1[e] = bf2f(k1[e]); }
            #pragma unroll
            for (int i = 0; i < 8; ++i){
                const float4 qa = *(const float4*)&qs[i][cgl];
                const float4 qb = *(const float4*)&qs[i][cgl + 4];
                d[0][i] += qa.x*kf0[0] + qa.y*kf0[1] + qa.z*kf0[2] + qa.w*kf0[3]
                         + qb.x*kf0[4] + qb.y*kf0[5] + qb.z*kf0[6] + qb.w*kf0[7];
                d[1][i] += qa.x*kf1[0] + qa.y*kf1[1] + qa.z*kf1[2] + qa.w*kf1[3]
                         + qb.x*kf1[4] + qb.y*kf1[5] + qb.z*kf1[6] + qb.w*kf1[7];
            }
        }
    }
    float s8[8] __attribute__((aligned(16)));
    #pragma unroll
    for (int i = 0; i < 8; ++i) s8[i] = 0.f;
    #pragma unroll
    for (int jj = 0; jj < 2; ++jj){
        float mx = d[jj][0];
        #pragma unroll
        for (int i = 1; i < 8; ++i) mx = fmaxf(mx, d[jj][i]);
        float e[8], ssum = 0.f;
        #pragma unroll
        for (int i = 0; i < 8; ++i){ e[i] = __expf((d[jj][i] - mx) * SCALE_); ssum += e[i]; }
        float inv = 1.f / ssum;
        #pragma unroll
        for (int i = 0; i < 8; ++i){
            float p = e[i]*inv + EPS_;
            ps[t + jj*256][i] = p;
            s8[i] += p;
        }
    }
    __syncthreads();
    float* scr = (float*)kt;
    *(float4*)&scr[t*8]     = *(float4*)&s8[0];
    *(float4*)&scr[t*8 + 4] = *(float4*)&s8[4];
    __syncthreads();
    if (t < 64){
        int i = t >> 3, part = t & 7;
        float s = 0.f;
        for (int u = 0; u < 32; ++u) s += scr[(part*32 + u)*8 + i];
        #pragma unroll
        for (int m = 1; m < 8; m <<= 1) s += __shfl_xor(s, m);
        if (part == 0) Spart[((size_t)b*8 + jb)*8 + i] = s;
    }
    __syncthreads();
    const int jseg = t >> 5, cg = t & 31;
    float ua[64] __attribute__((aligned(16)));
    #pragma unroll
    for (int e = 0; e < 64; ++e) ua[e] = 0.f;
    const unsigned short* vb = kv + row0*NOUT + 256 + cg*8;
    for (int jj = 0; jj < 64; ++jj){
        int j = jseg*64 + jj;
        ushort8 vv = *(const ushort8*)(vb + (size_t)j*NOUT);
        float vf[8];
        #pragma unroll
        for (int e = 0; e < 8; ++e) vf[e] = bf2f(vv[e]);
        const float4 p0 = *(const float4*)&ps[j][0];
        const float4 p1 = *(const float4*)&ps[j][4];
        const float pr[8] = {p0.x, p0.y, p0.z, p0.w, p1.x, p1.y, p1.z, p1.w};
        #pragma unroll
        for (int i = 0; i < 8; ++i)
            #pragma unroll
            for (int e = 0; e < 8; ++e)
                ua[i*8 + e] += pr[i] * vf[e];
    }
    for (int bound = 4; bound >= 1; bound >>= 1){
        __syncthreads();
        if (jseg >= bound && jseg < 2*bound){
            float* dst = &scr[((jseg - bound)*32 + cg) * 64];
            #pragma unroll
            for (int e4 = 0; e4 < 64; e4 += 4) *(float4*)&dst[e4] = *(float4*)&ua[e4];
        }
        __syncthreads();
        if (jseg < bound){
            const float* src = &scr[(jseg*32 + cg) * 64];
            #pragma unroll
            for (int e = 0; e < 64; ++e) ua[e] += src[e];
        }
    }
    if (jseg == 0){
        float* up = Upart + (((size_t)b*8 + jb)*8) * C_ + cg*8;
        #pragma unroll
        for (int i = 0; i < 8; ++i){
            *(float4*)&up[(size_t)i*C_]     = *(float4*)&ua[i*8];
            *(float4*)&up[(size_t)i*C_ + 4] = *(float4*)&ua[i*8 + 4];
        }
    }
}

// ---------------- per-iter: finalize updates + GRUCell -> slots2  (grid (B,8): 32 cols/block) ----------------
__global__ void gru_kernel(const float* __restrict__ slots, const float* __restrict__ Spart,
                           const float* __restrict__ Upart, const float* __restrict__ W_ih,
                           const float* __restrict__ b_ih, const float* __restrict__ W_hh,
                           const float* __restrict__ b_hh, float* __restrict__ slots2){
    __shared__ float upd[8][260], sp[8][260];
    const int t = threadIdx.x, b = blockIdx.x, ng = blockIdx.y;
    const int i = t >> 5, c0 = (t & 31) * 8;
    {
        float us[8];
        #pragma unroll
        for (int e = 0; e < 8; ++e) us[e] = 0.f;
        for (int jb = 0; jb < 8; ++jb){
            const float* up = Upart + (((size_t)b*8 + jb)*8 + i)*C_ + c0;
            float4 u0 = *(const float4*)up;
            float4 u1 = *(const float4*)(up + 4);
            us[0]+=u0.x; us[1]+=u0.y; us[2]+=u0.z; us[3]+=u0.w;
            us[4]+=u1.x; us[5]+=u1.y; us[6]+=u1.z; us[7]+=u1.w;
        }
        float S = 0.f;
        for (int jb = 0; jb < 8; ++jb) S += Spart[((size_t)b*8 + jb)*8 + i];
        float invS = 1.f / S;
        const float* slp = slots + ((size_t)b*8 + i)*C_ + c0;
        float4 s0v = *(const float4*)slp;
        float4 s1v = *(const float4*)(slp + 4);
        #pragma unroll
        for (int e = 0; e < 8; ++e) upd[i][c0 + e] = us[e] * invS;
        sp[i][c0+0]=s0v.x; sp[i][c0+1]=s0v.y; sp[i][c0+2]=s0v.z; sp[i][c0+3]=s0v.w;
        sp[i][c0+4]=s1v.x; sp[i][c0+5]=s1v.y; sp[i][c0+6]=s1v.z; sp[i][c0+7]=s1v.w;
    }
    __syncthreads();
    const int n = ng*32 + (t & 31);
    float xr = b_ih[n], xz = b_ih[256+n], xn = b_ih[512+n];
    float hr = b_hh[n], hz = b_hh[256+n], hn = b_hh[512+n];
    #pragma unroll 2
    for (int c = 0; c < 256; ++c){
        float uv = upd[i][c], sv = sp[i][c];
        const float* wi = W_ih + (size_t)c * 768 + n;
        const float* wh = W_hh + (size_t)c * 768 + n;
        xr += uv*wi[0];   xz += uv*wi[256]; xn += uv*wi[512];
        hr += sv*wh[0];   hz += sv*wh[256]; hn += sv*wh[512];
    }
    float rv = 1.f/(1.f + __expf(-(xr + hr)));
    float zv = 1.f/(1.f + __expf(-(xz + hz)));
    float nn = tanhf(xn + rv*hn);
    float o  = (1.f - zv)*nn + zv*sp[i][n];
    slots2[((size_t)b*8 + i)*C_ + n] = o;
}

// ---------------- per-iter: FFN part 1: h = relu(LN(slots2) @ W1 + b1)  (grid (B,8)) ----------------
__global__ void ffn1_kernel(const float* __restrict__ slots2, const float* __restrict__ gf,
                            const float* __restrict__ bf, const float* __restrict__ W1,
                            const float* __restrict__ b1, float* __restrict__ hbuf){
    __shared__ float pre[8][264];
    const int t = threadIdx.x, b = blockIdx.x, hg = blockIdx.y;
    const int i = t >> 5, c0 = (t & 31) * 8;
    {
        const float* spt = slots2 + ((size_t)b*8 + i)*C_ + c0;
        float v[8] __attribute__((aligned(16)));
        *(float4*)v       = *(const float4*)spt;
        *(float4*)(v + 4) = *(const float4*)(spt + 4);
        float sum = 0.f, sq = 0.f;
        #pragma unroll
        for (int e = 0; e < 8; ++e){ sum += v[e]; sq += v[e]*v[e]; }
        #pragma unroll
        for (int m = 1; m < 32; m <<= 1){ sum += __shfl_xor(sum, m); sq += __shfl_xor(sq, m); }
        float mean = sum * (1.f/256.f);
        float rstd = rsqrtf(sq * (1.f/256.f) - mean*mean + 1e-5f);
        #pragma unroll
        for (int e = 0; e < 8; ++e){
            int c = c0 + e;
            pre[i][c] = (v[e] - mean) * rstd * gf[c] + bf[c];
        }
    }
    __syncthreads();
    const int hcol = hg*32 + (t & 31);
    float acc = b1[hcol];
    #pragma unroll 4
    for (int c = 0; c < 256; ++c)
        acc += pre[i][c] * W1[(size_t)c*256 + hcol];
    hbuf[((size_t)b*8 + i)*C_ + hcol] = fmaxf(acc, 0.f);
}

// ---------------- per-iter: FFN part 2: slots = slots2 + h @ W2 + b2  (grid (B,8)) ----------------
__global__ void ffn2_kernel(const float* __restrict__ slots2, const float* __restrict__ hbuf,
                            const float* __restrict__ W2, const float* __restrict__ b2,
                            float* __restrict__ slots, float* __restrict__ dout){
    __shared__ float hs[8][264];
    const int t = threadIdx.x, b = blockIdx.x, og = blockIdx.y;
    const int i = t >> 5, c0 = (t & 31) * 8;
    {
        const float* hp = hbuf + ((size_t)b*8 + i)*C_ + c0;
        *(float4*)&hs[i][c0]     = *(const float4*)hp;
        *(float4*)&hs[i][c0 + 4] = *(const float4*)(hp + 4);
    }
    __syncthreads();
    const int ocol = og*32 + (t & 31);
    float acc = b2[ocol];
    #pragma unroll 4
    for (int m = 0; m < 256; ++m)
        acc += hs[i][m] * W2[(size_t)m*256 + ocol];
    size_t off = ((size_t)b*8 + i)*C_ + ocol;
    float val = slots2[off] + acc;
    slots[off] = val;
    dout[off]  = val;
}

extern "C" void kernel_launch(void* const* d_in, const int* in_sizes, int n_in,
                              void* d_out, int out_size, void* d_ws, size_t ws_size,
                              hipStream_t stream){
    const float* inputs = (const float*)d_in[0];
    const float* noise  = (const float*)d_in[1];
    const float* mu     = (const float*)d_in[2];
    const float* lsig   = (const float*)d_in[3];
    const float* g_in   = (const float*)d_in[4];
    const float* b_in   = (const float*)d_in[5];
    const float* g_s    = (const float*)d_in[6];
    const float* b_s    = (const float*)d_in[7];
    const float* g_ff   = (const float*)d_in[8];
    const float* b_ff   = (const float*)d_in[9];
    const float* Wq     = (const float*)d_in[10];
    const float* bq     = (const float*)d_in[11];
    const float* Wk     = (const float*)d_in[12];
    const float* bk     = (const float*)d_in[13];
    const float* Wv     = (const float*)d_in[14];
    const float* bv     = (const float*)d_in[15];
    const float* W_ih   = (const float*)d_in[16];
    const float* b_ih   = (const float*)d_in[17];
    const float* W_hh   = (const float*)d_in[18];
    const float* b_hh   = (const float*)d_in[19];
    const float* W1     = (const float*)d_in[20];
    const float* b1     = (const float*)d_in[21];
    const float* W2     = (const float*)d_in[22];
    const float* b2     = (const float*)d_in[23];

    char* ws = (char*)d_ws;
    unsigned short* WTf = (unsigned short*)(ws);              // 256 KB
    float* biasKV       = (float*)(ws + ((size_t)1  << 20));  // 2 KB
    float* qbuf         = (float*)(ws + ((size_t)2  << 20));  // 512 KB
    float* slots        = (float*)(ws + ((size_t)3  << 20));  // 512 KB
    float* Spart        = (float*)(ws + ((size_t)4  << 20));  // 16 KB
    float* Upart        = (float*)(ws + ((size_t)5  << 20));  // 4 MB
    float* slots2       = (float*)(ws + ((size_t)10 << 20));  // 512 KB
    float* hbuf         = (float*)(ws + ((size_t)11 << 20));  // 512 KB
    unsigned short* kv  = (unsigned short*)(ws + ((size_t)16 << 20)); // 256 MB

    prep_kernel<<<512, 256, 0, stream>>>(Wk, bk, Wv, bv, mu, lsig, noise, WTf, biasKV, slots);
    lnkv_kernel<<<M_/64, 512, 0, stream>>>(inputs, g_in, b_in, WTf, biasKV, kv);
    for (int it = 0; it < ITERS_; ++it){
        q_kernel<<<dim3(B_, 8), 256, 0, stream>>>(slots, Wq, bq, g_s, b_s, qbuf);
        attn_kernel<<<dim3(B_, 8), 256, 0, stream>>>(qbuf, kv, Spart, Upart);
        gru_kernel<<<dim3(B_, 8), 256, 0, stream>>>(slots, Spart, Upart, W_ih, b_ih, W_hh, b_hh, slots2);
        ffn1_kernel<<<dim3(B_, 8), 256, 0, stream>>>(slots2, g_ff, b_ff, W1, b1, hbuf);
        ffn2_kernel<<<dim3(B_, 8), 256, 0, stream>>>(slots2, hbuf, W2, b2, slots, (float*)d_out);
    }
}

// Round 3
// 795.720 us; speedup vs baseline: 1.9079x; 1.6792x over previous
//
#include <hip/hip_runtime.h>
#include <hip/hip_bf16.h>

#define B_ 64
#define N_ 4096
#define C_ 256
#define K_ 8
#define NOUT 512
#define M_ (B_*N_)
#define ITERS_ 3
#define SCALE_ 0.0625f
#define EPS_ 1e-8f

typedef __attribute__((ext_vector_type(4))) float f32x4;
typedef __attribute__((ext_vector_type(8))) __bf16 bf16x8;
typedef __attribute__((ext_vector_type(8))) unsigned short ushort8;
typedef __attribute__((ext_vector_type(4))) unsigned short ushort4v;

__device__ __forceinline__ unsigned short f2bf(float f){
    union { float f; unsigned u; } v; v.f = f;
    unsigned r = v.u + 0x7fffu + ((v.u >> 16) & 1u);
    return (unsigned short)(r >> 16);
}
__device__ __forceinline__ float bf2f(unsigned short h){
    union { unsigned u; float f; } v; v.u = ((unsigned)h) << 16;
    return v.f;
}

// ---------------- prep: WTf = [Wk|Wv]^T bf16 (MFMA-fragment-tiled), biasKV, slots init ----------------
__global__ void prep_kernel(const float* __restrict__ Wk, const float* __restrict__ bk,
                            const float* __restrict__ Wv, const float* __restrict__ bv,
                            const float* __restrict__ mu, const float* __restrict__ lsig,
                            const float* __restrict__ noise,
                            unsigned short* __restrict__ WTf, float* __restrict__ biasKV,
                            float* __restrict__ slots){
    int idx = blockIdx.x * 256 + threadIdx.x;      // 0..131071
    int c = idx >> 9, n = idx & 511;               // coalesced over n for W reads
    float w = (n < 256) ? Wk[c*256 + n] : Wv[c*256 + (n - 256)];
    int tile = (n >> 4) * 8 + (c >> 5);
    int lane = (n & 15) + (((c >> 3) & 3) << 4);
    WTf[tile*512 + lane*8 + (c & 7)] = f2bf(w);
    if (idx < NOUT) biasKV[idx] = (idx < 256) ? bk[idx] : bv[idx - 256];
    int sc = idx & 255;
    int si = (idx >> 8) & 7;
    slots[idx] = mu[sc] + expf(lsig[sc]) * noise[si*256 + sc];
}

// ---------------- fused LN(x) @ [Wk|Wv] + bias -> kv bf16 ----------------
__global__ __launch_bounds__(512, 4)
void lnkv_kernel(const float* __restrict__ x, const float* __restrict__ g, const float* __restrict__ bta,
                 const unsigned short* __restrict__ WTf, const float* __restrict__ biasKV,
                 unsigned short* __restrict__ kv){
    __shared__ __align__(16) unsigned short A[64*256];   // 32 KB: bf16 A-tile, then out-staging
    const int t = threadIdx.x;
    const int r0 = blockIdx.x * 64;
    const int row = t >> 3, sl = t & 7;

    float v[32];
    {
        const float* xr = x + (size_t)(r0 + row) * C_;
        #pragma unroll
        for (int q = 0; q < 4; ++q){
            *(float4*)&v[q*8]     = *(const float4*)(xr + q*64 + sl*8);
            *(float4*)&v[q*8 + 4] = *(const float4*)(xr + q*64 + sl*8 + 4);
        }
        float sum = 0.f, sq = 0.f;
        #pragma unroll
        for (int e = 0; e < 32; ++e){ sum += v[e]; sq += v[e]*v[e]; }
        #pragma unroll
        for (int m = 1; m < 8; m <<= 1){ sum += __shfl_xor(sum, m); sq += __shfl_xor(sq, m); }
        float mean = sum * (1.f/256.f);
        float rstd = rsqrtf(sq * (1.f/256.f) - mean*mean + 1e-5f);
        #pragma unroll
        for (int q = 0; q < 4; ++q){
            float4 g0 = *(const float4*)(g + q*64 + sl*8);
            float4 g1 = *(const float4*)(g + q*64 + sl*8 + 4);
            float4 b0 = *(const float4*)(bta + q*64 + sl*8);
            float4 b1 = *(const float4*)(bta + q*64 + sl*8 + 4);
            const float* gp0 = (const float*)&g0; const float* gp1 = (const float*)&g1;
            const float* bp0 = (const float*)&b0; const float* bp1 = (const float*)&b1;
            ushort8 pk;
            #pragma unroll
            for (int e = 0; e < 4; ++e){
                pk[e]   = f2bf((v[q*8+e]   - mean) * rstd * gp0[e] + bp0[e]);
                pk[4+e] = f2bf((v[q*8+4+e] - mean) * rstd * gp1[e] + bp1[e]);
            }
            int ch = (q*8 + sl) ^ (row & 7);
            *(ushort8*)&A[row*256 + ch*8] = pk;
        }
    }
    __syncthreads();

    const int w = t >> 6, l = t & 63, lr = l & 15, lg = l >> 4;
    f32x4 acc[4][4];   // [nt][mt]
    #pragma unroll
    for (int nt = 0; nt < 4; ++nt)
        #pragma unroll
        for (int mt = 0; mt < 4; ++mt) acc[nt][mt] = (f32x4){0.f,0.f,0.f,0.f};

    #pragma unroll
    for (int k = 0; k < 8; ++k){
        bf16x8 wf[4], xf[4];
        #pragma unroll
        for (int nt = 0; nt < 4; ++nt)
            wf[nt] = __builtin_bit_cast(bf16x8,
                *(const ushort8*)(WTf + (((w*4 + nt)*8 + k) << 9) + l*8));
        #pragma unroll
        for (int mt = 0; mt < 4; ++mt){
            int m = mt*16 + lr;
            int ch = (k*4 + lg) ^ (m & 7);
            xf[mt] = __builtin_bit_cast(bf16x8, *(const ushort8*)&A[m*256 + ch*8]);
        }
        #pragma unroll
        for (int nt = 0; nt < 4; ++nt)
            #pragma unroll
            for (int mt = 0; mt < 4; ++mt)
                acc[nt][mt] = __builtin_amdgcn_mfma_f32_16x16x32_bf16(wf[nt], xf[mt], acc[nt][mt], 0, 0, 0);
    }
    __syncthreads();

    char* S = (char*)A;
    const int rnd = w >> 2, sw = w & 3;
    #pragma unroll
    for (int r = 0; r < 2; ++r){
        if (rnd == r){
            #pragma unroll
            for (int nt = 0; nt < 4; ++nt){
                float4 b4 = *(const float4*)(biasKV + w*64 + nt*16 + lg*4);
                #pragma unroll
                for (int mt = 0; mt < 4; ++mt){
                    int m = mt*16 + lr;
                    ushort4v pk;
                    pk[0] = f2bf(acc[nt][mt][0] + b4.x);
                    pk[1] = f2bf(acc[nt][mt][1] + b4.y);
                    pk[2] = f2bf(acc[nt][mt][2] + b4.z);
                    pk[3] = f2bf(acc[nt][mt][3] + b4.w);
                    int byte = sw*8192 + m*128 + ((nt*32 + lg*8) ^ ((m & 15) << 3));
                    *(ushort4v*)(S + byte) = pk;
                }
            }
        }
        __syncthreads();
        {
            int swp = t >> 7, rem = t & 127, m = rem >> 1, half = rem & 1;
            unsigned short tmp[32];
            #pragma unroll
            for (int cck = 0; cck < 8; ++cck){
                int byte = swp*8192 + m*128 + ((half*64 + cck*8) ^ ((m & 15) << 3));
                *(ushort4v*)&tmp[cck*4] = *(const ushort4v*)(S + byte);
            }
            unsigned short* dst = kv + (size_t)(r0 + m)*NOUT + (r*4 + swp)*64 + half*32;
            *(ushort8*)(dst)      = *(ushort8*)&tmp[0];
            *(ushort8*)(dst + 8)  = *(ushort8*)&tmp[8];
            *(ushort8*)(dst + 16) = *(ushort8*)&tmp[16];
            *(ushort8*)(dst + 24) = *(ushort8*)&tmp[24];
        }
        __syncthreads();
    }
}

// ---------------- per-iter: q = LN_s(slots) @ Wq + bq  (grid (B,8)) ----------------
__global__ void q_kernel(const float* __restrict__ slots, const float* __restrict__ Wq,
                         const float* __restrict__ bq, const float* __restrict__ gs,
                         const float* __restrict__ bs, float* __restrict__ qout){
    __shared__ float sn[8][264];
    const int t = threadIdx.x, b = blockIdx.x, qg = blockIdx.y;
    const int i = t >> 5, c0 = (t & 31) * 8;
    {
        const float* sp = slots + ((size_t)b*K_ + i) * C_ + c0;
        float v[8] __attribute__((aligned(16)));
        *(float4*)v       = *(const float4*)sp;
        *(float4*)(v + 4) = *(const float4*)(sp + 4);
        float sum = 0.f, sq = 0.f;
        #pragma unroll
        for (int e = 0; e < 8; ++e){ sum += v[e]; sq += v[e]*v[e]; }
        #pragma unroll
        for (int m = 1; m < 32; m <<= 1){ sum += __shfl_xor(sum, m); sq += __shfl_xor(sq, m); }
        float mean = sum * (1.f/256.f);
        float rstd = rsqrtf(sq * (1.f/256.f) - mean*mean + 1e-5f);
        #pragma unroll
        for (int e = 0; e < 8; ++e){
            int c = c0 + e;
            sn[i][c] = (v[e] - mean) * rstd * gs[c] + bs[c];
        }
    }
    __syncthreads();
    const int col = qg*32 + (t & 31);
    float acc = bq[col];
    #pragma unroll 4
    for (int c = 0; c < 256; ++c)
        acc += sn[i][c] * Wq[(size_t)c*256 + col];
    qout[((size_t)b*K_ + i)*C_ + col] = acc;
}

// ---------------- per-iter: dots -> slot-softmax -> U partials (register-resident PV) ----------------
// grid (B, 8): 512 j per block, 256 threads.
__global__ __launch_bounds__(256, 2)
void attn_kernel(const float* __restrict__ q, const unsigned short* __restrict__ kv,
                 float* __restrict__ Spart, float* __restrict__ Upart){
    __shared__ __align__(16) char kt[512*64];   // 32KB: k-stage (QK) then v-stage (PV)
    __shared__ float qs[8][264];
    __shared__ float ps[512][8];
    __shared__ float swred[4][8];
    const int t = threadIdx.x, b = blockIdx.x, jb = blockIdx.y;
    const size_t row0 = (size_t)b * N_ + (size_t)jb * 512;
    {
        int i = t >> 5, c0 = (t & 31) * 8;
        const float* qp = q + ((size_t)b*K_ + i)*C_ + c0;
        *(float4*)&qs[i][c0]     = *(const float4*)qp;
        *(float4*)&qs[i][c0 + 4] = *(const float4*)(qp + 4);
    }
    float d[2][8];
    #pragma unroll
    for (int jj = 0; jj < 2; ++jj)
        #pragma unroll
        for (int i = 0; i < 8; ++i) d[jj][i] = 0.f;

    for (int cc = 0; cc < 256; cc += 32){
        __syncthreads();
        #pragma unroll
        for (int s = 0; s < 8; ++s){
            int r = s*64 + (t >> 2);
            int slot = (t & 3) ^ (r & 3);
            ushort8 kvv = *(const ushort8*)(kv + (row0 + r)*NOUT + cc + (t & 3)*8);
            *(ushort8*)(kt + r*64 + slot*16) = kvv;
        }
        __syncthreads();
        #pragma unroll
        for (int sub = 0; sub < 4; ++sub){
            const int cgl = cc + sub*8;
            ushort8 k0 = *(const ushort8*)(kt + t*64       + ((sub ^ (t & 3)) * 16));
            ushort8 k1 = *(const ushort8*)(kt + (t+256)*64 + ((sub ^ (t & 3)) * 16));
            float kf0[8], kf1[8];
            #pragma unroll
            for (int e = 0; e < 8; ++e){ kf0[e] = bf2f(k0[e]); kf1[e] = bf2f(k1[e]); }
            #pragma unroll
            for (int i = 0; i < 8; ++i){
                const float4 qa = *(const float4*)&qs[i][cgl];
                const float4 qb = *(const float4*)&qs[i][cgl + 4];
                d[0][i] += qa.x*kf0[0] + qa.y*kf0[1] + qa.z*kf0[2] + qa.w*kf0[3]
                         + qb.x*kf0[4] + qb.y*kf0[5] + qb.z*kf0[6] + qb.w*kf0[7];
                d[1][i] += qa.x*kf1[0] + qa.y*kf1[1] + qa.z*kf1[2] + qa.w*kf1[3]
                         + qb.x*kf1[4] + qb.y*kf1[5] + qb.z*kf1[6] + qb.w*kf1[7];
            }
        }
    }
    // slot-axis softmax (thread-local) + EPS; per-thread key-sums s8
    float s8[8];
    #pragma unroll
    for (int i = 0; i < 8; ++i) s8[i] = 0.f;
    #pragma unroll
    for (int jj = 0; jj < 2; ++jj){
        float mx = d[jj][0];
        #pragma unroll
        for (int i = 1; i < 8; ++i) mx = fmaxf(mx, d[jj][i]);
        float e[8], ssum = 0.f;
        #pragma unroll
        for (int i = 0; i < 8; ++i){ e[i] = __expf((d[jj][i] - mx) * SCALE_); ssum += e[i]; }
        float inv = 1.f / ssum;
        #pragma unroll
        for (int i = 0; i < 8; ++i){
            float p = e[i]*inv + EPS_;
            ps[t + jj*256][i] = p;
            s8[i] += p;
        }
    }
    // wave-level reduce of s8, then 4-wave combine
    #pragma unroll
    for (int i = 0; i < 8; ++i){
        float s = s8[i];
        #pragma unroll
        for (int m = 1; m < 64; m <<= 1) s += __shfl_xor(s, m);
        if ((t & 63) == 0) swred[t >> 6][i] = s;
    }
    __syncthreads();     // ps visible, swred visible, all QK kt reads done
    if (t < 8)
        Spart[((size_t)b*8 + jb)*8 + t] = swred[0][t] + swred[1][t] + swred[2][t] + swred[3][t];

    // ---- PV: register-resident accumulators, v staged via kt in 8 chunks of 64 rows ----
    const int islot = t >> 5, cg = t & 31;
    f32x4 ua0 = (f32x4){0.f,0.f,0.f,0.f}, ua1 = (f32x4){0.f,0.f,0.f,0.f};
    const int vrow = t >> 5;          // 0..7: row-in-group for staging
    const int vcol = (t & 31) * 8;    // col elems
    ushort8 stA[8], stB[8];
    {
        const unsigned short* vb = kv + (row0 + vrow)*NOUT + 256 + vcol;
        #pragma unroll
        for (int s = 0; s < 8; ++s) stA[s] = *(const ushort8*)(vb + (size_t)s*8*NOUT);
    }
    #pragma unroll
    for (int cp = 0; cp < 4; ++cp){
        // even chunk 2cp from stA
        {
            #pragma unroll
            for (int s = 0; s < 8; ++s)
                *(ushort8*)(kt + (s*8 + vrow)*512 + vcol*2) = stA[s];
            {   // prefetch chunk 2cp+1
                const unsigned short* vb = kv + (row0 + (2*cp+1)*64 + vrow)*NOUT + 256 + vcol;
                #pragma unroll
                for (int s = 0; s < 8; ++s) stB[s] = *(const ushort8*)(vb + (size_t)s*8*NOUT);
            }
            __syncthreads();
            #pragma unroll 2
            for (int jj = 0; jj < 64; ++jj){
                float p = ps[cp*128 + jj][islot];
                const ushort8 vv = *(const ushort8*)(kt + jj*512 + cg*16);
                ua0[0] += p * bf2f(vv[0]); ua0[1] += p * bf2f(vv[1]);
                ua0[2] += p * bf2f(vv[2]); ua0[3] += p * bf2f(vv[3]);
                ua1[0] += p * bf2f(vv[4]); ua1[1] += p * bf2f(vv[5]);
                ua1[2] += p * bf2f(vv[6]); ua1[3] += p * bf2f(vv[7]);
            }
            __syncthreads();
        }
        // odd chunk 2cp+1 from stB
        {
            #pragma unroll
            for (int s = 0; s < 8; ++s)
                *(ushort8*)(kt + (s*8 + vrow)*512 + vcol*2) = stB[s];
            if (cp < 3){   // prefetch chunk 2cp+2
                const unsigned short* vb = kv + (row0 + (2*cp+2)*64 + vrow)*NOUT + 256 + vcol;
                #pragma unroll
                for (int s = 0; s < 8; ++s) stA[s] = *(const ushort8*)(vb + (size_t)s*8*NOUT);
            }
            __syncthreads();
            #pragma unroll 2
            for (int jj = 0; jj < 64; ++jj){
                float p = ps[cp*128 + 64 + jj][islot];
                const ushort8 vv = *(const ushort8*)(kt + jj*512 + cg*16);
                ua0[0] += p * bf2f(vv[0]); ua0[1] += p * bf2f(vv[1]);
                ua0[2] += p * bf2f(vv[2]); ua0[3] += p * bf2f(vv[3]);
                ua1[0] += p * bf2f(vv[4]); ua1[1] += p * bf2f(vv[5]);
                ua1[2] += p * bf2f(vv[6]); ua1[3] += p * bf2f(vv[7]);
            }
            __syncthreads();
        }
    }
    {
        float* up = Upart + (((size_t)b*8 + jb)*8 + islot)*C_ + cg*8;
        float4 o0; o0.x = ua0[0]; o0.y = ua0[1]; o0.z = ua0[2]; o0.w = ua0[3];
        float4 o1; o1.x = ua1[0]; o1.y = ua1[1]; o1.z = ua1[2]; o1.w = ua1[3];
        *(float4*)up       = o0;
        *(float4*)(up + 4) = o1;
    }
}

// ---------------- per-iter: finalize updates + GRUCell -> slots2  (grid (B,8)) ----------------
__global__ void gru_kernel(const float* __restrict__ slots, const float* __restrict__ Spart,
                           const float* __restrict__ Upart, const float* __restrict__ W_ih,
                           const float* __restrict__ b_ih, const float* __restrict__ W_hh,
                           const float* __restrict__ b_hh, float* __restrict__ slots2){
    __shared__ float upd[8][260], sp[8][260];
    const int t = threadIdx.x, b = blockIdx.x, ng = blockIdx.y;
    const int i = t >> 5, c0 = (t & 31) * 8;
    {
        float us[8];
        #pragma unroll
        for (int e = 0; e < 8; ++e) us[e] = 0.f;
        for (int jb = 0; jb < 8; ++jb){
            const float* up = Upart + (((size_t)b*8 + jb)*8 + i)*C_ + c0;
            float4 u0 = *(const float4*)up;
            float4 u1 = *(const float4*)(up + 4);
            us[0]+=u0.x; us[1]+=u0.y; us[2]+=u0.z; us[3]+=u0.w;
            us[4]+=u1.x; us[5]+=u1.y; us[6]+=u1.z; us[7]+=u1.w;
        }
        float S = 0.f;
        for (int jb = 0; jb < 8; ++jb) S += Spart[((size_t)b*8 + jb)*8 + i];
        float invS = 1.f / S;
        const float* slp = slots + ((size_t)b*8 + i)*C_ + c0;
        float4 s0v = *(const float4*)slp;
        float4 s1v = *(const float4*)(slp + 4);
        #pragma unroll
        for (int e = 0; e < 8; ++e) upd[i][c0 + e] = us[e] * invS;
        sp[i][c0+0]=s0v.x; sp[i][c0+1]=s0v.y; sp[i][c0+2]=s0v.z; sp[i][c0+3]=s0v.w;
        sp[i][c0+4]=s1v.x; sp[i][c0+5]=s1v.y; sp[i][c0+6]=s1v.z; sp[i][c0+7]=s1v.w;
    }
    __syncthreads();
    const int n = ng*32 + (t & 31);
    float xr = b_ih[n], xz = b_ih[256+n], xn = b_ih[512+n];
    float hr = b_hh[n], hz = b_hh[256+n], hn = b_hh[512+n];
    #pragma unroll 2
    for (int c = 0; c < 256; ++c){
        float uv = upd[i][c], sv = sp[i][c];
        const float* wi = W_ih + (size_t)c * 768 + n;
        const float* wh = W_hh + (size_t)c * 768 + n;
        xr += uv*wi[0];   xz += uv*wi[256]; xn += uv*wi[512];
        hr += sv*wh[0];   hz += sv*wh[256]; hn += sv*wh[512];
    }
    float rv = 1.f/(1.f + __expf(-(xr + hr)));
    float zv = 1.f/(1.f + __expf(-(xz + hz)));
    float nn = tanhf(xn + rv*hn);
    float o  = (1.f - zv)*nn + zv*sp[i][n];
    slots2[((size_t)b*8 + i)*C_ + n] = o;
}

// ---------------- per-iter: FFN part 1 (grid (B,8)) ----------------
__global__ void ffn1_kernel(const float* __restrict__ slots2, const float* __restrict__ gf,
                            const float* __restrict__ bf, const float* __restrict__ W1,
                            const float* __restrict__ b1, float* __restrict__ hbuf){
    __shared__ float pre[8][264];
    const int t = threadIdx.x, b = blockIdx.x, hg = blockIdx.y;
    const int i = t >> 5, c0 = (t & 31) * 8;
    {
        const float* spt = slots2 + ((size_t)b*8 + i)*C_ + c0;
        float v[8] __attribute__((aligned(16)));
        *(float4*)v       = *(const float4*)spt;
        *(float4*)(v + 4) = *(const float4*)(spt + 4);
        float sum = 0.f, sq = 0.f;
        #pragma unroll
        for (int e = 0; e < 8; ++e){ sum += v[e]; sq += v[e]*v[e]; }
        #pragma unroll
        for (int m = 1; m < 32; m <<= 1){ sum += __shfl_xor(sum, m); sq += __shfl_xor(sq, m); }
        float mean = sum * (1.f/256.f);
        float rstd = rsqrtf(sq * (1.f/256.f) - mean*mean + 1e-5f);
        #pragma unroll
        for (int e = 0; e < 8; ++e){
            int c = c0 + e;
            pre[i][c] = (v[e] - mean) * rstd * gf[c] + bf[c];
        }
    }
    __syncthreads();
    const int hcol = hg*32 + (t & 31);
    float acc = b1[hcol];
    #pragma unroll 4
    for (int c = 0; c < 256; ++c)
        acc += pre[i][c] * W1[(size_t)c*256 + hcol];
    hbuf[((size_t)b*8 + i)*C_ + hcol] = fmaxf(acc, 0.f);
}

// ---------------- per-iter: FFN part 2 (grid (B,8)) ----------------
__global__ void ffn2_kernel(const float* __restrict__ slots2, const float* __restrict__ hbuf,
                            const float* __restrict__ W2, const float* __restrict__ b2,
                            float* __restrict__ slots, float* __restrict__ dout){
    __shared__ float hs[8][264];
    const int t = threadIdx.x, b = blockIdx.x, og = blockIdx.y;
    const int i = t >> 5, c0 = (t & 31) * 8;
    {
        const float* hp = hbuf + ((size_t)b*8 + i)*C_ + c0;
        *(float4*)&hs[i][c0]     = *(const float4*)hp;
        *(float4*)&hs[i][c0 + 4] = *(const float4*)(hp + 4);
    }
    __syncthreads();
    const int ocol = og*32 + (t & 31);
    float acc = b2[ocol];
    #pragma unroll 4
    for (int m = 0; m < 256; ++m)
        acc += hs[i][m] * W2[(size_t)m*256 + ocol];
    size_t off = ((size_t)b*8 + i)*C_ + ocol;
    float val = slots2[off] + acc;
    slots[off] = val;
    dout[off]  = val;
}

extern "C" void kernel_launch(void* const* d_in, const int* in_sizes, int n_in,
                              void* d_out, int out_size, void* d_ws, size_t ws_size,
                              hipStream_t stream){
    const float* inputs = (const float*)d_in[0];
    const float* noise  = (const float*)d_in[1];
    const float* mu     = (const float*)d_in[2];
    const float* lsig   = (const float*)d_in[3];
    const float* g_in   = (const float*)d_in[4];
    const float* b_in   = (const float*)d_in[5];
    const float* g_s    = (const float*)d_in[6];
    const float* b_s    = (const float*)d_in[7];
    const float* g_ff   = (const float*)d_in[8];
    const float* b_ff   = (const float*)d_in[9];
    const float* Wq     = (const float*)d_in[10];
    const float* bq     = (const float*)d_in[11];
    const float* Wk     = (const float*)d_in[12];
    const float* bk     = (const float*)d_in[13];
    const float* Wv     = (const float*)d_in[14];
    const float* bv     = (const float*)d_in[15];
    const float* W_ih   = (const float*)d_in[16];
    const float* b_ih   = (const float*)d_in[17];
    const float* W_hh   = (const float*)d_in[18];
    const float* b_hh   = (const float*)d_in[19];
    const float* W1     = (const float*)d_in[20];
    const float* b1     = (const float*)d_in[21];
    const float* W2     = (const float*)d_in[22];
    const float* b2     = (const float*)d_in[23];

    char* ws = (char*)d_ws;
    unsigned short* WTf = (unsigned short*)(ws);              // 256 KB
    float* biasKV       = (float*)(ws + ((size_t)1  << 20));  // 2 KB
    float* qbuf         = (float*)(ws + ((size_t)2  << 20));  // 512 KB
    float* slots        = (float*)(ws + ((size_t)3  << 20));  // 512 KB
    float* Spart        = (float*)(ws + ((size_t)4  << 20));  // 16 KB
    float* Upart        = (float*)(ws + ((size_t)5  << 20));  // 4 MB
    float* slots2       = (float*)(ws + ((size_t)10 << 20));  // 512 KB
    float* hbuf         = (float*)(ws + ((size_t)11 << 20));  // 512 KB
    unsigned short* kv  = (unsigned short*)(ws + ((size_t)16 << 20)); // 256 MB

    prep_kernel<<<512, 256, 0, stream>>>(Wk, bk, Wv, bv, mu, lsig, noise, WTf, biasKV, slots);
    lnkv_kernel<<<M_/64, 512, 0, stream>>>(inputs, g_in, b_in, WTf, biasKV, kv);
    for (int it = 0; it < ITERS_; ++it){
        q_kernel<<<dim3(B_, 8), 256, 0, stream>>>(slots, Wq, bq, g_s, b_s, qbuf);
        attn_kernel<<<dim3(B_, 8), 256, 0, stream>>>(qbuf, kv, Spart, Upart);
        gru_kernel<<<dim3(B_, 8), 256, 0, stream>>>(slots, Spart, Upart, W_ih, b_ih, W_hh, b_hh, slots2);
        ffn1_kernel<<<dim3(B_, 8), 256, 0, stream>>>(slots2, g_ff, b_ff, W1, b1, hbuf);
        ffn2_kernel<<<dim3(B_, 8), 256, 0, stream>>>(slots2, hbuf, W2, b2, slots, (float*)d_out);
    }
}